// Round 7
// baseline (355.697 us; speedup 1.0000x reference)
//
#include <hip/hip_runtime.h>
#include <math.h>

typedef float f2 __attribute__((ext_vector_type(2)));

namespace {
constexpr int TOUT = 32;            // output tile side
constexpr int HALO = 15;            // 16-tap VALID conv halo
constexpr int TIN  = TOUT + HALO;   // 47 rows of horizontal-conv output
constexpr int HSTR = 68;            // hb row stride in dwords (272 B, 16B-aligned)
constexpr int IMG  = 512;
constexpr int OUTW = IMG - HALO;    // 497
constexpr int NBLK = 16 * 16 * 96;  // 24576 blocks

struct GaussWin { float g[16]; };

__device__ __forceinline__ f2 fma2(f2 a, f2 b, f2 c) {
    return __builtin_elementwise_fma(a, b, c);
}

// round-half-up bf16 pack of two floats: [hi.bf16 : lo.bf16]
__device__ __forceinline__ unsigned pack_bf16(float hi, float lo) {
    const unsigned a = __float_as_uint(hi) + 0x8000u;
    const unsigned b = __float_as_uint(lo) + 0x8000u;
    return __builtin_amdgcn_perm(a, b, 0x07060302u);
}
}

// One block = one 32x32 output tile of one (batch,channel) plane.
//
// R6 post-mortem: spill-free packed-f32 kernel at 220 us, VALUBusy 44%,
// occupancy ~30% (~2.5 blocks/CU resident) -- latency-bound, LDS was the
// suspected occupancy limiter at 28 KB. This round: hb compressed to bf16
// (4 values {lin.a, lin.b, quad.q, quad.x} -> one uint2 per column),
// LDS 12.8 KB -> 8 blocks/CU (VGPR-capped). Numerics: bf16 round err is
// zero-mean ~1e-3 abs, averaged x0.43 by the vertical window; sgq/sg12
// cancellation leaves ~5e-4 random -> ssim-mean error ~1e-5 vs 8.28e-3
// threshold. Round-half-up (+0x8000) avoids truncation bias (~2e-3 abs
// final, 23% of budget -- not worth risking).
//
// Phase AB: 188 threads = 47 rows x 4 col-segments of 8 outputs. Stream 23
//   inputs in float4 chunks; signal-packed (f2 = {a,b} / {a^2+b^2, ab})
//   horizontal 16-tap conv (v_pk_fma_f32); MSE fused; bf16-pack + 4x
//   ds_write_b128 per thread.
// Phase C: 256 threads = 32 cols x 8 row-groups of 4. 19 b64 reads/thread
//   streamed in 4-row chunks; shl/and bf16 unpack; packed vertical conv;
//   SSIM map with v_rcp.
// Tail: per-block double2 partial (R2: same-address f64 atomics serialize
//   ~13 ns each); reduce_kernel sums.
template <bool TWO_STAGE>
__global__ __launch_bounds__(256)
void ssim_mse_kernel(
    const float* __restrict__ img1,
    const float* __restrict__ img2,
    GaussWin win,
    double2* __restrict__ partial,
    double*  __restrict__ accum)
{
    __shared__ unsigned hb[TIN][HSTR];  // 47*68*4 = 12,784 B
    __shared__ float red[2][4];

    const int tid = threadIdx.x;
    const int ox0 = blockIdx.x * TOUT;
    const int oy0 = blockIdx.y * TOUT;
    const size_t plane_off = (size_t)blockIdx.z * (IMG * IMG);
    const float* __restrict__ p1 = img1 + plane_off;
    const float* __restrict__ p2 = img2 + plane_off;

    float mse_local = 0.0f;

    // ---------------- Phase AB: load + MSE + horizontal conv ----------------
    if (tid < TIN * 4) {
        const int r   = tid >> 2;       // row 0..46
        const int seg = tid & 3;        // col segment: 8 outputs each
        const int gy  = oy0 + r;
        const int c0  = ox0 + 8 * seg;
        const bool ownrow = (r < TOUT);

        const int gyc = gy < IMG ? gy : (IMG - 1);
        const float* __restrict__ pa = p1 + (size_t)gyc * IMG;
        const float* __restrict__ pb = p2 + (size_t)gyc * IMG;
        const bool fast = (c0 + 23 <= IMG);

        f2 accl[8], accq[8];
        #pragma unroll
        for (int j = 0; j < 8; ++j) { accl[j] = f2{0,0}; accq[j] = f2{0,0}; }

        #pragma unroll
        for (int ch = 0; ch < 6; ++ch) {
            const int ib = 4 * ch;
            const int n  = (ch == 5) ? 3 : 4;

            f2 in[4];
            if (fast) {
                if (n == 4) {
                    const float4 la = *(const float4*)(pa + c0 + ib);
                    const float4 lb = *(const float4*)(pb + c0 + ib);
                    in[0] = f2{la.x, lb.x}; in[1] = f2{la.y, lb.y};
                    in[2] = f2{la.z, lb.z}; in[3] = f2{la.w, lb.w};
                } else {
                    const float2 la = *(const float2*)(pa + c0 + 20);
                    const float2 lb = *(const float2*)(pb + c0 + 20);
                    in[0] = f2{la.x, lb.x}; in[1] = f2{la.y, lb.y};
                    in[2] = f2{pa[c0 + 22], pb[c0 + 22]};
                }
            } else {
                #pragma unroll
                for (int t = 0; t < 4; ++t) {
                    if (t < n) {
                        const int gx = (c0 + ib + t) < IMG ? (c0 + ib + t) : (IMG - 1);
                        in[t] = f2{pa[gx], pb[gx]};
                    }
                }
            }

            #pragma unroll
            for (int t = 0; t < 4; ++t) {
                if (t >= n) continue;
                const int i = ib + t;
                const f2 v  = in[t];
                const f2 qx = f2{fmaf(v.x, v.x, v.y * v.y), v.x * v.y};
                if (i < 8 && ownrow) {       // owned pixel -> MSE
                    const float d = v.x - v.y;
                    mse_local = fmaf(d, d, mse_local);
                }
                const int jlo = (i > 15) ? (i - 15) : 0;
                const int jhi = (i < 7) ? i : 7;
                #pragma unroll
                for (int j = 0; j < 8; ++j) {
                    if (j < jlo || j > jhi) continue;
                    const float w = win.g[i - j];
                    const f2 w2 = f2{w, w};
                    accl[j] = fma2(w2, v,  accl[j]);
                    accq[j] = fma2(w2, qx, accq[j]);
                }
            }
        }

        // bf16-pack and store: 8 cols -> 8 uint2 -> 4 ds_write_b128
        const int cb = 16 * seg;        // dword offset of col 8*seg
        #pragma unroll
        for (int h = 0; h < 4; ++h) {   // each h covers 2 cols
            uint4 w;
            w.x = pack_bf16(accl[2*h].x,   accl[2*h].y);
            w.y = pack_bf16(accq[2*h].x,   accq[2*h].y);
            w.z = pack_bf16(accl[2*h+1].x, accl[2*h+1].y);
            w.w = pack_bf16(accq[2*h+1].x, accq[2*h+1].y);
            *(uint4*)&hb[r][cb + 4*h] = w;
        }
    }
    __syncthreads();

    // ---------------- Phase C: vertical conv + SSIM map ----------------
    float ssim_local = 0.0f;
    {
        const int c   = tid & 31;       // column 0..31
        const int rg  = tid >> 5;       // 0..7 -> rows 4rg..4rg+3
        const int yo0 = 4 * rg;
        const int limx = OUTW - ox0;
        const int limy = OUTW - oy0;

        f2 aL[4], aQ[4];
        #pragma unroll
        for (int j = 0; j < 4; ++j) { aL[j] = f2{0,0}; aQ[j] = f2{0,0}; }

        #pragma unroll
        for (int kb = 0; kb < 5; ++kb) {
            const int nk = (kb == 4) ? 3 : 4;
            f2 vL[4], vQ[4];
            #pragma unroll
            for (int t = 0; t < 4; ++t) {
                if (t < nk) {
                    const uint2 w = *(const uint2*)&hb[yo0 + 4 * kb + t][2 * c];
                    vL[t] = f2{__uint_as_float(w.x & 0xFFFF0000u),
                               __uint_as_float(w.x << 16)};
                    vQ[t] = f2{__uint_as_float(w.y & 0xFFFF0000u),
                               __uint_as_float(w.y << 16)};
                }
            }
            #pragma unroll
            for (int t = 0; t < 4; ++t) {
                if (t >= nk) continue;
                const int k = 4 * kb + t;
                const int jlo = (k > 15) ? (k - 15) : 0;
                const int jhi = (k < 3) ? k : 3;
                #pragma unroll
                for (int j = 0; j < 4; ++j) {
                    if (j < jlo || j > jhi) continue;
                    const float w = win.g[k - j];
                    const f2 w2 = f2{w, w};
                    aL[j] = fma2(w2, vL[t], aL[j]);
                    aQ[j] = fma2(w2, vQ[t], aQ[j]);
                }
            }
        }

        const float C1u = 1.0e-4f;   // (0.01*255)^2 / 255^2
        const float C2u = 9.0e-4f;   // (0.03*255)^2 / 255^2
        #pragma unroll
        for (int j = 0; j < 4; ++j) {
            const float mu1  = aL[j].x, mu2 = aL[j].y;
            const float mu12 = mu1 * mu2;
            const float musq = fmaf(mu1, mu1, mu2 * mu2);
            const float sgq  = aQ[j].x - musq;     // sigma1^2 + sigma2^2
            const float sg12 = aQ[j].y - mu12;
            const float num  = fmaf(2.0f, mu12, C1u) * fmaf(2.0f, sg12, C2u);
            const float den  = (musq + C1u) * (sgq + C2u);
            const float val  = num * __builtin_amdgcn_rcpf(den);
            if (c < limx && (yo0 + j) < limy) ssim_local += val;
        }
    }

    // ---------------- Block reduction + partial write ----------------
    #pragma unroll
    for (int off = 32; off > 0; off >>= 1) {
        mse_local  += __shfl_down(mse_local,  off, 64);
        ssim_local += __shfl_down(ssim_local, off, 64);
    }
    const int wave = tid >> 6;
    if ((tid & 63) == 0) { red[0][wave] = mse_local; red[1][wave] = ssim_local; }
    __syncthreads();
    if (tid == 0) {
        const double m = (double)red[0][0] + (double)red[0][1]
                       + (double)red[0][2] + (double)red[0][3];
        const double s = (double)red[1][0] + (double)red[1][1]
                       + (double)red[1][2] + (double)red[1][3];
        if (TWO_STAGE) {
            const int bid = (int)blockIdx.x
                          + 16 * ((int)blockIdx.y + 16 * (int)blockIdx.z);
            partial[bid] = make_double2(m, s);
        } else {
            atomicAdd(&accum[0], m);
            atomicAdd(&accum[1], s);
        }
    }
}

// Single block, 1024 threads: 24576 partials = 1024 x 24 exactly.
__global__ __launch_bounds__(1024) void reduce_kernel(
    const double2* __restrict__ partial,
    float* __restrict__ out)
{
    __shared__ double sm[16], ss[16];
    const int tid = threadIdx.x;
    double m = 0.0, s = 0.0;
    #pragma unroll
    for (int k = 0; k < 24; ++k) {
        const double2 p = partial[tid + 1024 * k];
        m += p.x; s += p.y;
    }
    #pragma unroll
    for (int off = 32; off > 0; off >>= 1) {
        m += __shfl_down(m, off, 64);
        s += __shfl_down(s, off, 64);
    }
    if ((tid & 63) == 0) { sm[tid >> 6] = m; ss[tid >> 6] = s; }
    __syncthreads();
    if (tid == 0) {
        double M = 0.0, S = 0.0;
        #pragma unroll
        for (int w = 0; w < 16; ++w) { M += sm[w]; S += ss[w]; }
        const double mse  = M / 25165824.0;   // 32*3*512*512
        const double ssim = S / 23712864.0;   // 32*3*497*497
        out[0] = (float)(0.7 * mse + 0.3 * (1.0 - ssim));
    }
}

__global__ void finalize_kernel(const double* __restrict__ accum,
                                float* __restrict__ out)
{
    const double mse  = accum[0] / 25165824.0;
    const double ssim = accum[1] / 23712864.0;
    out[0] = (float)(0.7 * mse + 0.3 * (1.0 - ssim));
}

extern "C" void kernel_launch(void* const* d_in, const int* in_sizes, int n_in,
                              void* d_out, int out_size, void* d_ws, size_t ws_size,
                              hipStream_t stream) {
    const float* img1 = (const float*)d_in[0];
    const float* img2 = (const float*)d_in[1];
    float* out = (float*)d_out;

    GaussWin win;
    {
        double g[16], s = 0.0;
        for (int i = 0; i < 16; ++i) {
            const double c = (double)i - 7.5;
            g[i] = exp(-(c * c) / 4.5);
            s += g[i];
        }
        for (int i = 0; i < 16; ++i) win.g[i] = (float)(g[i] / s);
    }

    dim3 grid(16, 16, 96);   // 16x16 tiles of 497x497, 96 = 32*3 planes
    if (ws_size >= (size_t)NBLK * sizeof(double2)) {
        double2* partial = (double2*)d_ws;
        ssim_mse_kernel<true><<<grid, dim3(256), 0, stream>>>(
            img1, img2, win, partial, nullptr);
        reduce_kernel<<<1, dim3(1024), 0, stream>>>(partial, out);
    } else {
        double* accum = (double*)d_ws;
        hipMemsetAsync(d_ws, 0, 2 * sizeof(double), stream);
        ssim_mse_kernel<false><<<grid, dim3(256), 0, stream>>>(
            img1, img2, win, nullptr, accum);
        finalize_kernel<<<1, 1, 0, stream>>>(accum, out);
    }
}

// Round 8
// 245.177 us; speedup vs baseline: 1.4508x; 1.4508x over previous
//
#include <hip/hip_runtime.h>
#include <math.h>
#include <string.h>

typedef __attribute__((ext_vector_type(8))) short bf16x8;
typedef __attribute__((ext_vector_type(4))) float f32x4;

namespace {
constexpr int TOUT = 32;            // output tile side
constexpr int IMG  = 512;
constexpr int HALO = 15;
constexpr int OUTW = IMG - HALO;    // 497
constexpr int NBLK = 16 * 16 * 96;  // 24576 blocks

struct WinPk { unsigned w[8]; };    // 16 bf16 Gaussian weights, packed pairs

// pack two pre-rounded (+0x8000) float bit patterns into [hi.bf16 : lo.bf16]
__device__ __forceinline__ unsigned prm(unsigned hi, unsigned lo) {
    return __builtin_amdgcn_perm(hi, lo, 0x07060302u);
}
}

// One block = one 32x32 output tile of one (batch,channel) plane.
// MFMA formulation: 16-tap conv = GEMM vs constant banded matrix
// W[k][n] = g[k-n] (zero outside band). One per-lane banded fragment
// wf[j] = g[(q*8+j)-(lane&15)] serves as B-operand (horizontal) and
// A-operand (vertical) of mfma_f32_16x16x32_bf16.
//
// Phase A (192 thr): stage 48x48 bf16 patches of 4 signals {a,b,a^2+b^2,ab}
//   (computed FROM the bf16-rounded a,b -> exact mu^2/E[x^2] consistency);
//   row47/col47 zero pad (K=32 windows read them with zero weight; must not
//   be NaN). MSE fused on owned 32x32 in fp32.
// Phase H: wave w = signal w: 3 Mtiles(rows) x 2 Ntiles(outcols) MFMA
//   (A = patch rows x cols b128-loaded, B = wf); C[row][outcol] ->
//   bf16 pack -> HB[sig][outcol][row] (b64 store, reg pairs).
// Phase V: wave w = output quadrant: per signal one MFMA (A = wf,
//   B = HB[sig][outcol][hbrow] b128), C[outrow][outcol] fp32 in regs ->
//   SSIM rational map -> masked sum.
// Tail: per-block double2 partial (R2: same-address f64 atomics serialize
//   ~13 ns each); reduce_kernel sums.
template <bool TWO_STAGE>
__global__ __launch_bounds__(256)
void ssim_mse_kernel(const float* __restrict__ img1,
                     const float* __restrict__ img2,
                     WinPk wpk,
                     double2* __restrict__ partial,
                     double*  __restrict__ accum)
{
    __shared__ unsigned short S[4][48][48];   // 18,432 B  raw signal planes
    __shared__ unsigned short HB[4][32][48];  // 12,288 B  [sig][outcol][hbrow]
    __shared__ unsigned short gt[64];         // banded-weight lookup
    __shared__ float red[2][4];

    const int tid = threadIdx.x;
    const int ox0 = blockIdx.x * TOUT;
    const int oy0 = blockIdx.y * TOUT;
    const size_t plane_off = (size_t)blockIdx.z * (IMG * IMG);
    const float* __restrict__ p1 = img1 + plane_off;
    const float* __restrict__ p2 = img2 + plane_off;

    float mse_local = 0.0f, ssim_local = 0.0f;

    // ---- weight table: gt[i] = bf16 g[i-16] for i in [16,32), else 0 ----
    if (tid < 16) gt[tid] = 0;
    else if (tid >= 32 && tid < 64) gt[tid] = 0;
    else if (tid == 16) {
        #pragma unroll
        for (int k = 0; k < 8; ++k)
            *(unsigned*)&gt[16 + 2 * k] = wpk.w[k];
    }

    // ---------------- Phase A: stage signals + MSE ----------------
    if (tid < 192) {
        const int r  = tid >> 2;        // 0..47
        const int cs = tid & 3;         // 12-col segment
        const int c0 = 12 * cs;
        if (r == 47) {                  // zero pad row
            #pragma unroll
            for (int p = 0; p < 4; ++p)
                #pragma unroll
                for (int h = 0; h < 6; ++h)
                    *(unsigned*)&S[p][47][c0 + 2 * h] = 0u;
        } else {
            const int gy  = oy0 + r;
            const int gyc = gy < IMG ? gy : IMG - 1;
            const float* __restrict__ pa = p1 + (size_t)gyc * IMG;
            const float* __restrict__ pb = p2 + (size_t)gyc * IMG;
            float Af[12], Bf[12];
            if (ox0 + c0 + 12 <= IMG) {
                #pragma unroll
                for (int v = 0; v < 3; ++v) {
                    const float4 va = *(const float4*)(pa + ox0 + c0 + 4 * v);
                    const float4 vb = *(const float4*)(pb + ox0 + c0 + 4 * v);
                    Af[4*v+0] = va.x; Af[4*v+1] = va.y; Af[4*v+2] = va.z; Af[4*v+3] = va.w;
                    Bf[4*v+0] = vb.x; Bf[4*v+1] = vb.y; Bf[4*v+2] = vb.z; Bf[4*v+3] = vb.w;
                }
            } else {
                #pragma unroll
                for (int j = 0; j < 12; ++j) {
                    int gx = ox0 + c0 + j; gx = gx < IMG ? gx : IMG - 1;
                    Af[j] = pa[gx]; Bf[j] = pb[gx];
                }
            }
            if (r < TOUT) {             // MSE on owned pixels, fp32 exact
                #pragma unroll
                for (int j = 0; j < 12; ++j) {
                    if (c0 + j < TOUT) {
                        const float d = Af[j] - Bf[j];
                        mse_local = fmaf(d, d, mse_local);
                    }
                }
            }
            #pragma unroll
            for (int h = 0; h < 6; ++h) {
                const unsigned a0 = __float_as_uint(Af[2*h])   + 0x8000u;
                const unsigned a1 = __float_as_uint(Af[2*h+1]) + 0x8000u;
                const unsigned b0 = __float_as_uint(Bf[2*h])   + 0x8000u;
                const unsigned b1 = __float_as_uint(Bf[2*h+1]) + 0x8000u;
                const float ar0 = __uint_as_float(a0 & 0xFFFF0000u);
                const float ar1 = __uint_as_float(a1 & 0xFFFF0000u);
                const float br0 = __uint_as_float(b0 & 0xFFFF0000u);
                const float br1 = __uint_as_float(b1 & 0xFFFF0000u);
                const unsigned q0 = __float_as_uint(fmaf(ar0, ar0, br0 * br0)) + 0x8000u;
                const unsigned q1 = __float_as_uint(fmaf(ar1, ar1, br1 * br1)) + 0x8000u;
                const unsigned x0 = __float_as_uint(ar0 * br0) + 0x8000u;
                const unsigned x1 = __float_as_uint(ar1 * br1) + 0x8000u;
                unsigned wA = prm(a1, a0), wB = prm(b1, b0);
                unsigned wQ = prm(q1, q0), wX = prm(x1, x0);
                if (cs == 3 && h == 5) {   // col 47 = zero pad
                    wA &= 0xFFFFu; wB &= 0xFFFFu; wQ &= 0xFFFFu; wX &= 0xFFFFu;
                }
                *(unsigned*)&S[0][r][c0 + 2*h] = wA;
                *(unsigned*)&S[1][r][c0 + 2*h] = wB;
                *(unsigned*)&S[2][r][c0 + 2*h] = wQ;
                *(unsigned*)&S[3][r][c0 + 2*h] = wX;
            }
        }
    }
    __syncthreads();

    const int m15 = tid & 15;
    const int q4  = (tid >> 4) & 3;
    const int wid = tid >> 6;

    // banded weight fragment, identical for every wave:
    // wf[j] = g[(q4*8+j) - m15]  (zero outside band)
    bf16x8 wf;
    {
        const int base = q4 * 8 - m15 + 16;   // +j -> index into gt, in [1,47]
        #pragma unroll
        for (int j = 0; j < 8; ++j)
            wf[j] = (short)gt[base + j];
    }

    // ---------------- Phase H: horizontal conv via MFMA ----------------
    {
        #pragma unroll
        for (int Mt = 0; Mt < 3; ++Mt) {
            #pragma unroll
            for (int Nt = 0; Nt < 2; ++Nt) {
                const bf16x8 af =
                    *(const bf16x8*)&S[wid][Mt * 16 + m15][Nt * 16 + q4 * 8];
                f32x4 c = {0.f, 0.f, 0.f, 0.f};
                c = __builtin_amdgcn_mfma_f32_16x16x32_bf16(af, wf, c, 0, 0, 0);
                // C: row = Mt*16 + q4*4 + reg, outcol = Nt*16 + m15
                const unsigned lo = prm(__float_as_uint(c[1]) + 0x8000u,
                                        __float_as_uint(c[0]) + 0x8000u);
                const unsigned hi = prm(__float_as_uint(c[3]) + 0x8000u,
                                        __float_as_uint(c[2]) + 0x8000u);
                uint2 wv; wv.x = lo; wv.y = hi;
                *(uint2*)&HB[wid][Nt * 16 + m15][Mt * 16 + q4 * 4] = wv;
            }
        }
    }
    __syncthreads();

    // ---------------- Phase V: vertical conv via MFMA + SSIM ----------------
    {
        const int Rt = wid >> 1, Ct = wid & 1;   // output quadrant
        const int ko = Rt * 16 + q4 * 8;         // hbrow K-offset
        const f32x4 z = {0.f, 0.f, 0.f, 0.f};
        const bf16x8 f0 = *(const bf16x8*)&HB[0][Ct * 16 + m15][ko];
        const bf16x8 f1 = *(const bf16x8*)&HB[1][Ct * 16 + m15][ko];
        const bf16x8 f2 = *(const bf16x8*)&HB[2][Ct * 16 + m15][ko];
        const bf16x8 f3 = *(const bf16x8*)&HB[3][Ct * 16 + m15][ko];
        const f32x4 M1 = __builtin_amdgcn_mfma_f32_16x16x32_bf16(wf, f0, z, 0, 0, 0);
        const f32x4 M2 = __builtin_amdgcn_mfma_f32_16x16x32_bf16(wf, f1, z, 0, 0, 0);
        const f32x4 Qm = __builtin_amdgcn_mfma_f32_16x16x32_bf16(wf, f2, z, 0, 0, 0);
        const f32x4 Xm = __builtin_amdgcn_mfma_f32_16x16x32_bf16(wf, f3, z, 0, 0, 0);

        const float C1u = 1.0e-4f;   // (0.01*255)^2 / 255^2
        const float C2u = 9.0e-4f;   // (0.03*255)^2 / 255^2
        const int ocol  = ox0 + Ct * 16 + m15;
        const int orow0 = oy0 + Rt * 16 + q4 * 4;
        #pragma unroll
        for (int g = 0; g < 4; ++g) {
            const float mu1  = M1[g], mu2 = M2[g];
            const float mu12 = mu1 * mu2;
            const float musq = fmaf(mu1, mu1, mu2 * mu2);
            const float sgq  = Qm[g] - musq;     // sigma1^2 + sigma2^2
            const float sg12 = Xm[g] - mu12;
            const float num  = fmaf(2.0f, mu12, C1u) * fmaf(2.0f, sg12, C2u);
            const float den  = (musq + C1u) * (sgq + C2u);
            const float val  = num * __builtin_amdgcn_rcpf(den);
            if (ocol < OUTW && (orow0 + g) < OUTW) ssim_local += val;
        }
    }

    // ---------------- Block reduction + partial write ----------------
    #pragma unroll
    for (int off = 32; off > 0; off >>= 1) {
        mse_local  += __shfl_down(mse_local,  off, 64);
        ssim_local += __shfl_down(ssim_local, off, 64);
    }
    if ((tid & 63) == 0) { red[0][wid] = mse_local; red[1][wid] = ssim_local; }
    __syncthreads();
    if (tid == 0) {
        const double m = (double)red[0][0] + (double)red[0][1]
                       + (double)red[0][2] + (double)red[0][3];
        const double s = (double)red[1][0] + (double)red[1][1]
                       + (double)red[1][2] + (double)red[1][3];
        if (TWO_STAGE) {
            const int bid = (int)blockIdx.x
                          + 16 * ((int)blockIdx.y + 16 * (int)blockIdx.z);
            partial[bid] = make_double2(m, s);
        } else {
            atomicAdd(&accum[0], m);
            atomicAdd(&accum[1], s);
        }
    }
}

// Single block, 1024 threads: 24576 partials = 1024 x 24 exactly.
__global__ __launch_bounds__(1024) void reduce_kernel(
    const double2* __restrict__ partial,
    float* __restrict__ out)
{
    __shared__ double sm[16], ss[16];
    const int tid = threadIdx.x;
    double m = 0.0, s = 0.0;
    #pragma unroll
    for (int k = 0; k < 24; ++k) {
        const double2 p = partial[tid + 1024 * k];
        m += p.x; s += p.y;
    }
    #pragma unroll
    for (int off = 32; off > 0; off >>= 1) {
        m += __shfl_down(m, off, 64);
        s += __shfl_down(s, off, 64);
    }
    if ((tid & 63) == 0) { sm[tid >> 6] = m; ss[tid >> 6] = s; }
    __syncthreads();
    if (tid == 0) {
        double M = 0.0, S = 0.0;
        #pragma unroll
        for (int w = 0; w < 16; ++w) { M += sm[w]; S += ss[w]; }
        const double mse  = M / 25165824.0;   // 32*3*512*512
        const double ssim = S / 23712864.0;   // 32*3*497*497
        out[0] = (float)(0.7 * mse + 0.3 * (1.0 - ssim));
    }
}

__global__ void finalize_kernel(const double* __restrict__ accum,
                                float* __restrict__ out)
{
    const double mse  = accum[0] / 25165824.0;
    const double ssim = accum[1] / 23712864.0;
    out[0] = (float)(0.7 * mse + 0.3 * (1.0 - ssim));
}

extern "C" void kernel_launch(void* const* d_in, const int* in_sizes, int n_in,
                              void* d_out, int out_size, void* d_ws, size_t ws_size,
                              hipStream_t stream) {
    const float* img1 = (const float*)d_in[0];
    const float* img2 = (const float*)d_in[1];
    float* out = (float*)d_out;

    // Gaussian window -> bf16 (RNE) -> packed pairs
    WinPk wpk;
    {
        double g[16], s = 0.0;
        for (int i = 0; i < 16; ++i) {
            const double c = (double)i - 7.5;
            g[i] = exp(-(c * c) / 4.5);
            s += g[i];
        }
        unsigned short h[16];
        for (int i = 0; i < 16; ++i) {
            const float gf = (float)(g[i] / s);
            unsigned u;
            memcpy(&u, &gf, 4);
            u += 0x7FFFu + ((u >> 16) & 1u);   // round-to-nearest-even
            h[i] = (unsigned short)(u >> 16);
        }
        for (int k = 0; k < 8; ++k)
            wpk.w[k] = (unsigned)h[2 * k] | ((unsigned)h[2 * k + 1] << 16);
    }

    dim3 grid(16, 16, 96);   // 16x16 tiles of 497x497, 96 = 32*3 planes
    if (ws_size >= (size_t)NBLK * sizeof(double2)) {
        double2* partial = (double2*)d_ws;
        ssim_mse_kernel<true><<<grid, dim3(256), 0, stream>>>(
            img1, img2, wpk, partial, nullptr);
        reduce_kernel<<<1, dim3(1024), 0, stream>>>(partial, out);
    } else {
        double* accum = (double*)d_ws;
        hipMemsetAsync(d_ws, 0, 2 * sizeof(double), stream);
        ssim_mse_kernel<false><<<grid, dim3(256), 0, stream>>>(
            img1, img2, wpk, nullptr, accum);
        finalize_kernel<<<1, 1, 0, stream>>>(accum, out);
    }
}